// Round 2
// baseline (176.705 us; speedup 1.0000x reference)
//
#include <hip/hip_runtime.h>
#include <stdint.h>

#define TOKENS  256
#define INF     4096
#define OUTF    11008
#define NGROUPS 32

#define BM 64
#define BN 128
#define BK 32
#define NTHREADS 256

typedef __attribute__((ext_vector_type(2))) _Float16 f16x2;
typedef __attribute__((ext_vector_type(8))) _Float16 f16x8;
typedef __attribute__((ext_vector_type(2))) __fp16   fp16v2;   // builtin return type
typedef __attribute__((ext_vector_type(4))) float    f32x4;

union U32H2 { uint32_t u; f16x2 h; };
union H8    { f16x2 h2[4]; f16x8 h8; };
union PK    { fp16v2 p; f16x2 h; };    // bit-cast cvt_pkrtz result

// K-slot permutation note: within each 8-k chunk (one qweight row r), slots are
// filled pairwise as (w_j, w_{j+4}) for j=0..3, i.e. slot 2j -> k=8r+j,
// slot 2j+1 -> k=8r+j+4. A-staging applies the SAME permutation, so the MFMA
// k-reduction is over a consistent bijection of k. B k-chunks are additionally
// XOR-swizzled by (col>>3)&3 to kill LDS write bank conflicts.

__global__ __launch_bounds__(NTHREADS, 2)
void qlin_mfma(const float* __restrict__ x,
               const uint32_t* __restrict__ qweight,
               const uint32_t* __restrict__ qzeros,
               const float* __restrict__ scales,
               const float* __restrict__ bias,
               float* __restrict__ out)
{
    __shared__ alignas(16) _Float16 As[BM][BK + 8];   // 64 x 40 fp16, row = 80 B
    __shared__ alignas(16) _Float16 Bs[BN][BK + 8];   // 128 x 40 fp16

    const int tid = threadIdx.x;
    const int bx  = blockIdx.x;      // OUTF/BN = 86
    const int by  = blockIdx.y;      // TOKENS/BM = 4

    // ---- A staging map: thread -> (row, 8-k chunk) ----
    const int am = tid >> 2;         // 0..63
    const int ar = tid & 3;          // 0..3
    const float* xrow = x + (size_t)(by * BM + am) * INF + ar * 8;

    // ---- B staging map: thread -> (col, rows {br, br+2}) ----
    const int bc   = tid & 127;      // 0..127
    const int br   = tid >> 7;       // 0..1
    const int bn   = bx * BN + bc;   // global out-feature
    const int bswz = (bc >> 3) & 3;  // k-chunk swizzle for this column

    // ---- compute map ----
    const int lane = tid & 63;
    const int quad = lane >> 4;
    const int l16  = lane & 15;
    const int wv   = tid >> 6;
    const int wm   = wv >> 1;        // 0..1 : rows wm*32 + mi*16
    const int wn   = wv & 1;         // 0..1 : cols wn*64 + ni*16

    f32x4 acc[2][4];
#pragma unroll
    for (int i = 0; i < 2; ++i)
#pragma unroll
        for (int j = 0; j < 4; ++j)
            acc[i][j] = f32x4{0.f, 0.f, 0.f, 0.f};

    // ---- prologue prefetch (iter 0) ----
    f32x4 pa0 = *(const f32x4*)(xrow + 0);
    f32x4 pa1 = *(const f32x4*)(xrow + 4);
    uint32_t pq0 = qweight[(size_t)(br)     * OUTF + bn];
    uint32_t pq1 = qweight[(size_t)(br + 2) * OUTF + bn];

    for (int g = 0; g < NGROUPS; ++g) {
        // per-group dequant constants for this thread's column
        const float    s   = scales[g * OUTF + bn];
        const uint32_t qzv = qzeros[g * (OUTF / 8) + (bn >> 3)];
        const int      z   = (int)((qzv >> (4 * (bn & 7))) & 15u) + 1;
        const _Float16 hs  = (_Float16)s;
        const _Float16 hz  = (_Float16)(-(float)(1024 + z));
        const f16x2 hs2 = {hs, hs};
        const f16x2 hz2 = {hz, hz};

#pragma unroll
        for (int t4 = 0; t4 < 4; ++t4) {
            const int it = (g << 2) + t4;

            // ---- stage A: fp32 -> fp16 (pkrtz), permuted (x_j, x_{j+4}) pairs ----
            {
                H8 ah;
                PK p0, p1, p2, p3;
                p0.p = __builtin_amdgcn_cvt_pkrtz(pa0[0], pa1[0]);
                p1.p = __builtin_amdgcn_cvt_pkrtz(pa0[1], pa1[1]);
                p2.p = __builtin_amdgcn_cvt_pkrtz(pa0[2], pa1[2]);
                p3.p = __builtin_amdgcn_cvt_pkrtz(pa0[3], pa1[3]);
                ah.h2[0] = p0.h;
                ah.h2[1] = p1.h;
                ah.h2[2] = p2.h;
                ah.h2[3] = p3.h;
                *(f16x8*)&As[am][ar * 8] = ah.h8;
            }

            // ---- stage B: packed int4 dequant -> fp16 ----
            {
                const uint32_t qq[2] = {pq0, pq1};
#pragma unroll
                for (int rr = 0; rr < 2; ++rr) {
                    const int r = br + rr * 2;        // k-chunk 0..3
                    H8 bh;
#pragma unroll
                    for (int jp = 0; jp < 4; ++jp) {
                        U32H2 u;
                        u.u = ((qq[rr] >> (4 * jp)) & 0x000F000Fu) | 0x64006400u;
                        // (1024+w) + (-(1024+z)) exact, then * s : one rounding
                        bh.h2[jp] = (u.h + hz2) * hs2;
                    }
                    *(f16x8*)&Bs[bc][(r ^ bswz) * 8] = bh.h8;
                }
            }

            __syncthreads();

            // ---- prefetch next iter's globals (overlaps with MFMA below) ----
            const int itn = (it < 127) ? it + 1 : 127;   // clamp: last prefetch unused
            pa0 = *(const f32x4*)(xrow + itn * BK);
            pa1 = *(const f32x4*)(xrow + itn * BK + 4);
            pq0 = qweight[(size_t)(itn * 4 + br)     * OUTF + bn];
            pq1 = qweight[(size_t)(itn * 4 + br + 2) * OUTF + bn];

            // ---- MFMA ----
            f16x8 af[2], bf[4];
#pragma unroll
            for (int mi = 0; mi < 2; ++mi)
                af[mi] = *(const f16x8*)&As[wm * 32 + mi * 16 + l16][quad * 8];
#pragma unroll
            for (int ni = 0; ni < 4; ++ni) {
                const int c = wn * 64 + ni * 16 + l16;
                bf[ni] = *(const f16x8*)&Bs[c][(quad ^ ((c >> 3) & 3)) * 8];
            }
#pragma unroll
            for (int mi = 0; mi < 2; ++mi)
#pragma unroll
                for (int ni = 0; ni < 4; ++ni)
                    acc[mi][ni] = __builtin_amdgcn_mfma_f32_16x16x32_f16(
                        af[mi], bf[ni], acc[mi][ni], 0, 0, 0);

            __syncthreads();
        }
    }

    // ---- epilogue: C/D layout col=lane&15, row=quad*4+reg (m89-verified) ----
#pragma unroll
    for (int ni = 0; ni < 4; ++ni) {
        const int col = bx * BN + wn * 64 + ni * 16 + l16;
        const float bv = bias[col];
#pragma unroll
        for (int mi = 0; mi < 2; ++mi) {
            const int row0 = by * BM + wm * 32 + mi * 16 + quad * 4;
#pragma unroll
            for (int rg = 0; rg < 4; ++rg)
                out[(size_t)(row0 + rg) * OUTF + col] = acc[mi][ni][rg] + bv;
        }
    }
}

extern "C" void kernel_launch(void* const* d_in, const int* in_sizes, int n_in,
                              void* d_out, int out_size, void* d_ws, size_t ws_size,
                              hipStream_t stream) {
    const float*    xx = (const float*)d_in[0];
    const uint32_t* qw = (const uint32_t*)d_in[1];
    const uint32_t* qz = (const uint32_t*)d_in[2];
    const float*    sc = (const float*)d_in[3];
    const float*    bs = (const float*)d_in[4];
    float* out = (float*)d_out;

    dim3 grid(OUTF / BN, TOKENS / BM);   // 86 x 4 = 344 blocks
    qlin_mfma<<<grid, NTHREADS, 0, stream>>>(xx, qw, qz, sc, bs, out);
}

// Round 3
// 122.011 us; speedup vs baseline: 1.4483x; 1.4483x over previous
//
#include <hip/hip_runtime.h>
#include <stdint.h>

#define TOKENS  256
#define INF     4096
#define OUTF    11008
#define NGROUPS 32
#define NPHASE  16            // K split into 16 phases of 256
#define NTH     256

typedef __attribute__((ext_vector_type(2))) _Float16 f16x2;
typedef __attribute__((ext_vector_type(8))) _Float16 f16x8;
typedef __attribute__((ext_vector_type(2))) __fp16   pkh2;
typedef __attribute__((ext_vector_type(4))) float    f32x4;

union U32H2 { uint32_t u; f16x2 h; };
union H8    { f16x2 h2[4]; f16x8 h8; };
union PK    { pkh2 p; f16x2 h; };

__device__ __forceinline__ void gl2lds16(const void* g, void* l) {
    __builtin_amdgcn_global_load_lds(
        (const __attribute__((address_space(1))) uint32_t*)g,
        (__attribute__((address_space(3))) uint32_t*)l, 16, 0, 0);
}

// LDS column swizzle: stored 16B-chunk col = logical ^ F(m&15). Gives 32 distinct
// cols across the 64 lanes of a frag ds_read_b128 -> 2-way bank aliasing (free).
__device__ __forceinline__ int Fswz(int m4) {
    return (m4 & 0xF) | (((m4 ^ (m4 >> 1)) & 1) << 4);
}

// ---------------- pre-kernel: x fp32 -> fp16, (j, j+4) pair-permuted ----------
// x16[row][8c + 2j + 0] = x[row][8c + j]; x16[row][8c + 2j + 1] = x[row][8c + j + 4]
__global__ __launch_bounds__(NTH)
void cvt_x(const float* __restrict__ x, _Float16* __restrict__ x16) {
    const int t   = blockIdx.x * NTH + threadIdx.x;   // 0 .. 131071
    const int row = t >> 9;
    const int c   = t & 511;
    const float* p = x + (size_t)row * INF + c * 8;
    f32x4 v0 = *(const f32x4*)p;
    f32x4 v1 = *(const f32x4*)(p + 4);
    H8 o; PK k0, k1, k2, k3;
    k0.p = __builtin_amdgcn_cvt_pkrtz(v0[0], v1[0]);
    k1.p = __builtin_amdgcn_cvt_pkrtz(v0[1], v1[1]);
    k2.p = __builtin_amdgcn_cvt_pkrtz(v0[2], v1[2]);
    k3.p = __builtin_amdgcn_cvt_pkrtz(v0[3], v1[3]);
    o.h2[0] = k0.h; o.h2[1] = k1.h; o.h2[2] = k2.h; o.h2[3] = k3.h;
    *(f16x8*)(x16 + (size_t)row * INF + c * 8) = o.h8;
}

// ---------------- main kernel: BM=64 x BN=128, B direct-from-global ----------
__global__ __launch_bounds__(NTH, 2)
void qlin_main(const _Float16* __restrict__ x16,
               const uint32_t* __restrict__ qweight,
               const uint32_t* __restrict__ qzeros,
               const float* __restrict__ scales,
               const float* __restrict__ bias,
               float* __restrict__ out)
{
    __shared__ alignas(16) _Float16 As[2][64 * 256];   // 2 x 32KB double buffer

    const int tid = threadIdx.x;
    const int bx  = blockIdx.x >> 2;   // 0..85  (out-feature block)
    const int by  = blockIdx.x & 3;    // 0..3   (token block)  -- same-bx blocks adjacent

    const int lane = tid & 63;
    const int quad = lane >> 4;
    const int l16  = lane & 15;
    const int wv   = tid >> 6;         // 0..3, wave's 32-col strip

    // ---- A fill map (global_load_lds, lane-linear slots) ----
    const int rowoff = (tid >> 5) & 7;
    const int sclin  = tid & 31;
    const int row0   = by * 64;
    const uint32_t aoffE = (uint32_t)((row0 + rowoff)     * (INF * 2) + (sclin ^ Fswz(rowoff))     * 16);
    const uint32_t aoffO = (uint32_t)((row0 + 8 + rowoff) * (INF * 2) + (sclin ^ Fswz(8 + rowoff)) * 16);
    const char* x16b = (const char*)x16;
    _Float16* ldsW = &As[0][0];
    const int ldsSlotBase = wv * 512;  // halves; + i*2048 per instr; +16384 per buf

    // ---- B map ----
    const int col0 = bx * 128 + wv * 32 + l16;   // nf=0 column
    const int col1 = col0 + 16;                  // nf=1 column
    const int bOff0 = quad * OUTF + col0;
    const int bOff1 = quad * OUTF + col1;
    const int zsh = (col0 & 7) * 4;              // same for col1

    // ---- frag read swizzle ----
    const int fsw = Fswz(l16);

    f32x4 acc[4][2];
#pragma unroll
    for (int mi = 0; mi < 4; ++mi)
#pragma unroll
        for (int nf = 0; nf < 2; ++nf)
            acc[mi][nf] = f32x4{0.f, 0.f, 0.f, 0.f};

    uint32_t Breg[2][16];
    float    sS[2][4];       // [par][gh*2+nf]
    uint32_t qZ[2][4];

    // ================= prologue: phase 0 prefetch =================
#pragma unroll
    for (int ii = 0; ii < 4; ++ii) {
        gl2lds16(x16b + aoffE + ii * 131072, ldsW + (2 * ii)     * 2048 + ldsSlotBase);
        gl2lds16(x16b + aoffO + ii * 131072, ldsW + (2 * ii + 1) * 2048 + ldsSlotBase);
    }
#pragma unroll
    for (int s = 0; s < 8; ++s) {
        const uint32_t* qp = qweight + (size_t)(s * 4) * OUTF;
        Breg[0][2 * s + 0] = qp[bOff0];
        Breg[0][2 * s + 1] = qp[bOff1];
    }
    sS[0][0] = scales[0 * OUTF + col0]; sS[0][1] = scales[0 * OUTF + col1];
    sS[0][2] = scales[1 * OUTF + col0]; sS[0][3] = scales[1 * OUTF + col1];
    qZ[0][0] = qzeros[0 * (OUTF / 8) + (col0 >> 3)]; qZ[0][1] = qzeros[0 * (OUTF / 8) + (col1 >> 3)];
    qZ[0][2] = qzeros[1 * (OUTF / 8) + (col0 >> 3)]; qZ[0][3] = qzeros[1 * (OUTF / 8) + (col1 >> 3)];
    __syncthreads();

    // ================= phase loop =================
#pragma unroll
    for (int p = 0; p < NPHASE; ++p) {
        const int par = p & 1;
        const int np  = par ^ 1;

        // ---- issue next phase's A (other LDS buf) + B/scale/zero (regs) ----
        if (p < NPHASE - 1) {
            const int pn = p + 1;
            const uint32_t pb = (uint32_t)(pn * 512);   // byte step per phase in a row
            _Float16* ldsN = ldsW + np * 16384;
#pragma unroll
            for (int ii = 0; ii < 4; ++ii) {
                gl2lds16(x16b + aoffE + ii * 131072 + pb, ldsN + (2 * ii)     * 2048 + ldsSlotBase);
                gl2lds16(x16b + aoffO + ii * 131072 + pb, ldsN + (2 * ii + 1) * 2048 + ldsSlotBase);
            }
            const uint32_t* qpb = qweight + (size_t)(pn * 32) * OUTF;
#pragma unroll
            for (int s = 0; s < 8; ++s) {
                const uint32_t* qp = qpb + (size_t)(s * 4) * OUTF;
                Breg[np][2 * s + 0] = qp[bOff0];
                Breg[np][2 * s + 1] = qp[bOff1];
            }
            const int g0 = 2 * pn, g1 = 2 * pn + 1;
            sS[np][0] = scales[g0 * OUTF + col0]; sS[np][1] = scales[g0 * OUTF + col1];
            sS[np][2] = scales[g1 * OUTF + col0]; sS[np][3] = scales[g1 * OUTF + col1];
            qZ[np][0] = qzeros[g0 * (OUTF / 8) + (col0 >> 3)]; qZ[np][1] = qzeros[g0 * (OUTF / 8) + (col1 >> 3)];
            qZ[np][2] = qzeros[g1 * (OUTF / 8) + (col0 >> 3)]; qZ[np][3] = qzeros[g1 * (OUTF / 8) + (col1 >> 3)];
        }

        // ---- per-group dequant constants for this phase ----
        f16x2 hs2[2][2], hz2[2][2];
#pragma unroll
        for (int gh = 0; gh < 2; ++gh)
#pragma unroll
            for (int nf = 0; nf < 2; ++nf) {
                const float s = sS[par][gh * 2 + nf];
                const int   z = (int)((qZ[par][gh * 2 + nf] >> zsh) & 15u) + 1025;  // 1024 + (z+1)
                const _Float16 hs = (_Float16)s;
                const _Float16 hz = (_Float16)(-(float)z);
                hs2[gh][nf] = f16x2{hs, hs};
                hz2[gh][nf] = f16x2{hz, hz};
            }

        // ---- compute: 8 ksteps of 32 ----
        const _Float16* buf = ldsW + par * 16384;
#pragma unroll
        for (int s = 0; s < 8; ++s) {
            const int gh = s >> 2;
            f16x8 af[4];
#pragma unroll
            for (int mi = 0; mi < 4; ++mi) {
                const int m  = mi * 16 + l16;
                const int sc = (s * 4 + quad) ^ fsw;
                af[mi] = *(const f16x8*)(buf + m * 256 + sc * 8);
            }
#pragma unroll
            for (int nf = 0; nf < 2; ++nf) {
                const uint32_t q = Breg[par][2 * s + nf];
                H8 b;
#pragma unroll
                for (int j = 0; j < 4; ++j) {
                    U32H2 u;
                    u.u = ((q >> (4 * j)) & 0x000F000Fu) | 0x64006400u;
                    b.h2[j] = (u.h + hz2[gh][nf]) * hs2[gh][nf];   // exact (w-z), one mul-round
                }
#pragma unroll
                for (int mi = 0; mi < 4; ++mi)
                    acc[mi][nf] = __builtin_amdgcn_mfma_f32_16x16x32_f16(
                        af[mi], b.h8, acc[mi][nf], 0, 0, 0);
            }
        }

        __syncthreads();   // drains next-phase loads; releases this buf
    }

    // ================= epilogue =================
#pragma unroll
    for (int nf = 0; nf < 2; ++nf) {
        const int col = (nf == 0) ? col0 : col1;
        const float bv = bias[col];
#pragma unroll
        for (int mi = 0; mi < 4; ++mi) {
            const int r0 = by * 64 + mi * 16 + quad * 4;
#pragma unroll
            for (int rg = 0; rg < 4; ++rg)
                out[(size_t)(r0 + rg) * OUTF + col] = acc[mi][nf][rg] + bv;
        }
    }
}

// ---------------- fallback (proven R2 kernel) if ws too small ----------------
__global__ __launch_bounds__(NTH, 2)
void qlin_fb(const float* __restrict__ x,
             const uint32_t* __restrict__ qweight,
             const uint32_t* __restrict__ qzeros,
             const float* __restrict__ scales,
             const float* __restrict__ bias,
             float* __restrict__ out)
{
    __shared__ alignas(16) _Float16 Asb[64][40];
    __shared__ alignas(16) _Float16 Bsb[128][40];
    const int tid = threadIdx.x;
    const int bx = blockIdx.x, by = blockIdx.y;
    const int am = tid >> 2, ar = tid & 3;
    const float* xrow = x + (size_t)(by * 64 + am) * INF + ar * 8;
    const int bc = tid & 127, br = tid >> 7;
    const int bn = bx * 128 + bc;
    const int bswz = (bc >> 3) & 3;
    const int lane = tid & 63, quad = lane >> 4, l16 = lane & 15;
    const int wv = tid >> 6, wm = wv >> 1, wn = wv & 1;
    f32x4 acc[2][4];
#pragma unroll
    for (int i = 0; i < 2; ++i)
#pragma unroll
        for (int j = 0; j < 4; ++j) acc[i][j] = f32x4{0.f, 0.f, 0.f, 0.f};
    f32x4 pa0 = *(const f32x4*)(xrow + 0);
    f32x4 pa1 = *(const f32x4*)(xrow + 4);
    uint32_t pq0 = qweight[(size_t)br * OUTF + bn];
    uint32_t pq1 = qweight[(size_t)(br + 2) * OUTF + bn];
    for (int g = 0; g < NGROUPS; ++g) {
        const float s = scales[g * OUTF + bn];
        const uint32_t qzv = qzeros[g * (OUTF / 8) + (bn >> 3)];
        const int z = (int)((qzv >> (4 * (bn & 7))) & 15u) + 1;
        const _Float16 hs = (_Float16)s;
        const _Float16 hz = (_Float16)(-(float)(1024 + z));
        const f16x2 hs2 = {hs, hs}, hz2 = {hz, hz};
#pragma unroll
        for (int t4 = 0; t4 < 4; ++t4) {
            const int it = (g << 2) + t4;
            { H8 ah; PK p0, p1, p2, p3;
              p0.p = __builtin_amdgcn_cvt_pkrtz(pa0[0], pa1[0]);
              p1.p = __builtin_amdgcn_cvt_pkrtz(pa0[1], pa1[1]);
              p2.p = __builtin_amdgcn_cvt_pkrtz(pa0[2], pa1[2]);
              p3.p = __builtin_amdgcn_cvt_pkrtz(pa0[3], pa1[3]);
              ah.h2[0] = p0.h; ah.h2[1] = p1.h; ah.h2[2] = p2.h; ah.h2[3] = p3.h;
              *(f16x8*)&Asb[am][ar * 8] = ah.h8; }
            { const uint32_t qq[2] = {pq0, pq1};
#pragma unroll
              for (int rr = 0; rr < 2; ++rr) {
                  const int r = br + rr * 2; H8 bh;
#pragma unroll
                  for (int jp = 0; jp < 4; ++jp) {
                      U32H2 u; u.u = ((qq[rr] >> (4 * jp)) & 0x000F000Fu) | 0x64006400u;
                      bh.h2[jp] = (u.h + hz2) * hs2;
                  }
                  *(f16x8*)&Bsb[bc][(r ^ bswz) * 8] = bh.h8;
              } }
            __syncthreads();
            const int itn = (it < 127) ? it + 1 : 127;
            pa0 = *(const f32x4*)(xrow + itn * 32);
            pa1 = *(const f32x4*)(xrow + itn * 32 + 4);
            pq0 = qweight[(size_t)(itn * 4 + br) * OUTF + bn];
            pq1 = qweight[(size_t)(itn * 4 + br + 2) * OUTF + bn];
            f16x8 af[2], bf[4];
#pragma unroll
            for (int mi = 0; mi < 2; ++mi)
                af[mi] = *(const f16x8*)&Asb[wm * 32 + mi * 16 + l16][quad * 8];
#pragma unroll
            for (int ni = 0; ni < 4; ++ni) {
                const int c = wn * 64 + ni * 16 + l16;
                bf[ni] = *(const f16x8*)&Bsb[c][(quad ^ ((c >> 3) & 3)) * 8];
            }
#pragma unroll
            for (int mi = 0; mi < 2; ++mi)
#pragma unroll
                for (int ni = 0; ni < 4; ++ni)
                    acc[mi][ni] = __builtin_amdgcn_mfma_f32_16x16x32_f16(
                        af[mi], bf[ni], acc[mi][ni], 0, 0, 0);
            __syncthreads();
        }
    }
#pragma unroll
    for (int ni = 0; ni < 4; ++ni) {
        const int col = bx * 128 + wn * 64 + ni * 16 + l16;
        const float bv = bias[col];
#pragma unroll
        for (int mi = 0; mi < 2; ++mi) {
            const int row0 = by * 64 + wm * 32 + mi * 16 + quad * 4;
#pragma unroll
            for (int rg = 0; rg < 4; ++rg)
                out[(size_t)(row0 + rg) * OUTF + col] = acc[mi][ni][rg] + bv;
        }
    }
}

extern "C" void kernel_launch(void* const* d_in, const int* in_sizes, int n_in,
                              void* d_out, int out_size, void* d_ws, size_t ws_size,
                              hipStream_t stream) {
    const float*    xx = (const float*)d_in[0];
    const uint32_t* qw = (const uint32_t*)d_in[1];
    const uint32_t* qz = (const uint32_t*)d_in[2];
    const float*    sc = (const float*)d_in[3];
    const float*    bs = (const float*)d_in[4];
    float* out = (float*)d_out;

    const size_t x16_bytes = (size_t)TOKENS * INF * sizeof(_Float16);  // 2 MB
    if (ws_size >= x16_bytes) {
        _Float16* x16 = (_Float16*)d_ws;
        cvt_x<<<(TOKENS * INF / 8) / NTH, NTH, 0, stream>>>(xx, x16);
        qlin_main<<<(OUTF / 128) * (TOKENS / 64), NTH, 0, stream>>>(x16, qw, qz, sc, bs, out);
    } else {
        dim3 grid(OUTF / 128, TOKENS / 64);
        qlin_fb<<<grid, NTH, 0, stream>>>(xx, qw, qz, sc, bs, out);
    }
}

// Round 4
// 120.634 us; speedup vs baseline: 1.4648x; 1.0114x over previous
//
#include <hip/hip_runtime.h>
#include <stdint.h>

#define TOKENS  256
#define INF     4096
#define OUTF    11008
#define NGROUPS 32
#define NPHASE  16            // K split into 16 phases of 256
#define NTH     256

typedef __attribute__((ext_vector_type(2))) _Float16 f16x2;
typedef __attribute__((ext_vector_type(8))) _Float16 f16x8;
typedef __attribute__((ext_vector_type(2))) __fp16   pkh2;
typedef __attribute__((ext_vector_type(4))) float    f32x4;

union U32H2 { uint32_t u; f16x2 h; };
union H8    { f16x2 h2[4]; f16x8 h8; };
union PK    { pkh2 p; f16x2 h; };

__device__ __forceinline__ void gl2lds16(const void* g, void* l) {
    __builtin_amdgcn_global_load_lds(
        (const __attribute__((address_space(1))) uint32_t*)g,
        (__attribute__((address_space(3))) uint32_t*)l, 16, 0, 0);
}

// LDS column swizzle: stored 16B-chunk col = logical ^ F(m&15). Gives 32 distinct
// cols across the 64 lanes of a frag ds_read_b128 -> 2-way bank aliasing (free).
__device__ __forceinline__ int Fswz(int m4) {
    return (m4 & 0xF) | (((m4 ^ (m4 >> 1)) & 1) << 4);
}

// ---------------- pre-kernel: x fp32 -> fp16, (j, j+4) pair-permuted ----------
__global__ __launch_bounds__(NTH)
void cvt_x(const float* __restrict__ x, _Float16* __restrict__ x16) {
    const int t   = blockIdx.x * NTH + threadIdx.x;   // 0 .. 131071
    const int row = t >> 9;
    const int c   = t & 511;
    const float* p = x + (size_t)row * INF + c * 8;
    f32x4 v0 = *(const f32x4*)p;
    f32x4 v1 = *(const f32x4*)(p + 4);
    H8 o; PK k0, k1, k2, k3;
    k0.p = __builtin_amdgcn_cvt_pkrtz(v0[0], v1[0]);
    k1.p = __builtin_amdgcn_cvt_pkrtz(v0[1], v1[1]);
    k2.p = __builtin_amdgcn_cvt_pkrtz(v0[2], v1[2]);
    k3.p = __builtin_amdgcn_cvt_pkrtz(v0[3], v1[3]);
    o.h2[0] = k0.h; o.h2[1] = k1.h; o.h2[2] = k2.h; o.h2[3] = k3.h;
    *(f16x8*)(x16 + (size_t)row * INF + c * 8) = o.h8;
}

// ---------------- main kernel: BM=64 x BN=128, B direct-from-global ----------
// PHASE body as macro so the double-buffer index PAR stays compile-time while
// the outer loop stays ROLLED (R3's full 16x unroll blew the 32KB I$: ~60KB of
// code, all pipes idle at 50us).
__global__ __launch_bounds__(NTH, 2)
void qlin_main(const _Float16* __restrict__ x16,
               const uint32_t* __restrict__ qweight,
               const uint32_t* __restrict__ qzeros,
               const float* __restrict__ scales,
               const float* __restrict__ bias,
               float* __restrict__ out)
{
    __shared__ alignas(16) _Float16 As[2][64 * 256];   // 2 x 32KB double buffer

    const int tid = threadIdx.x;
    const int bx  = blockIdx.x >> 2;   // 0..85  (out-feature block)
    const int by  = blockIdx.x & 3;    // 0..3   (token block)

    const int lane = tid & 63;
    const int quad = lane >> 4;
    const int l16  = lane & 15;
    const int wv   = tid >> 6;         // 0..3, wave's 32-col strip

    // ---- A fill map (global_load_lds, lane-linear slots) ----
    const int rowoff = (tid >> 5) & 7;
    const int sclin  = tid & 31;
    const int row0   = by * 64;
    const uint32_t aoffE = (uint32_t)((row0 + rowoff)     * (INF * 2) + (sclin ^ Fswz(rowoff))     * 16);
    const uint32_t aoffO = (uint32_t)((row0 + 8 + rowoff) * (INF * 2) + (sclin ^ Fswz(8 + rowoff)) * 16);
    const char* x16b = (const char*)x16;
    _Float16* ldsW = &As[0][0];
    const int ldsSlotBase = wv * 512;  // halves; + i*2048 per instr; +16384 per buf

    // ---- B map ----
    const int col0 = bx * 128 + wv * 32 + l16;   // nf=0 column
    const int col1 = col0 + 16;                  // nf=1 column
    const int bOff0 = quad * OUTF + col0;
    const int bOff1 = quad * OUTF + col1;
    const int zsh = (col0 & 7) * 4;              // same for col1

    const int fsw = Fswz(l16);

    f32x4 acc[4][2];
#pragma unroll
    for (int mi = 0; mi < 4; ++mi)
#pragma unroll
        for (int nf = 0; nf < 2; ++nf)
            acc[mi][nf] = f32x4{0.f, 0.f, 0.f, 0.f};

    uint32_t Breg[2][16];
    float    sS[2][4];       // [par][gh*2+nf]
    uint32_t qZ[2][4];

    // ================= prologue: phase 0 prefetch =================
#pragma unroll
    for (int ii = 0; ii < 4; ++ii) {
        gl2lds16(x16b + aoffE + ii * 131072, ldsW + (2 * ii)     * 2048 + ldsSlotBase);
        gl2lds16(x16b + aoffO + ii * 131072, ldsW + (2 * ii + 1) * 2048 + ldsSlotBase);
    }
#pragma unroll
    for (int s = 0; s < 8; ++s) {
        const uint32_t* qp = qweight + (size_t)(s * 4) * OUTF;
        Breg[0][2 * s + 0] = qp[bOff0];
        Breg[0][2 * s + 1] = qp[bOff1];
    }
    sS[0][0] = scales[0 * OUTF + col0]; sS[0][1] = scales[0 * OUTF + col1];
    sS[0][2] = scales[1 * OUTF + col0]; sS[0][3] = scales[1 * OUTF + col1];
    qZ[0][0] = qzeros[0 * (OUTF / 8) + (col0 >> 3)]; qZ[0][1] = qzeros[0 * (OUTF / 8) + (col1 >> 3)];
    qZ[0][2] = qzeros[1 * (OUTF / 8) + (col0 >> 3)]; qZ[0][3] = qzeros[1 * (OUTF / 8) + (col1 >> 3)];
    __syncthreads();

    // ================= phase loop (ROLLED, 2 phases per iteration) ============
#define PHASE_BODY(PAR, P, DO_PREFETCH)                                          \
    {                                                                            \
        const int p_ = (P);                                                      \
        if (DO_PREFETCH) {                                                       \
            const int pn = p_ + 1;                                               \
            const uint32_t pb = (uint32_t)(pn * 512);                            \
            _Float16* ldsN = ldsW + (1 - (PAR)) * 16384;                         \
            _Pragma("unroll")                                                    \
            for (int ii = 0; ii < 4; ++ii) {                                     \
                gl2lds16(x16b + aoffE + ii * 131072 + pb,                        \
                         ldsN + (2 * ii)     * 2048 + ldsSlotBase);              \
                gl2lds16(x16b + aoffO + ii * 131072 + pb,                        \
                         ldsN + (2 * ii + 1) * 2048 + ldsSlotBase);              \
            }                                                                    \
            const uint32_t* qpb = qweight + (size_t)(pn * 32) * OUTF;            \
            _Pragma("unroll")                                                    \
            for (int s = 0; s < 8; ++s) {                                        \
                const uint32_t* qp = qpb + (size_t)(s * 4) * OUTF;               \
                Breg[1 - (PAR)][2 * s + 0] = qp[bOff0];                          \
                Breg[1 - (PAR)][2 * s + 1] = qp[bOff1];                          \
            }                                                                    \
            const int g0 = 2 * pn, g1 = 2 * pn + 1;                              \
            sS[1 - (PAR)][0] = scales[g0 * OUTF + col0];                         \
            sS[1 - (PAR)][1] = scales[g0 * OUTF + col1];                         \
            sS[1 - (PAR)][2] = scales[g1 * OUTF + col0];                         \
            sS[1 - (PAR)][3] = scales[g1 * OUTF + col1];                         \
            qZ[1 - (PAR)][0] = qzeros[g0 * (OUTF / 8) + (col0 >> 3)];            \
            qZ[1 - (PAR)][1] = qzeros[g0 * (OUTF / 8) + (col1 >> 3)];            \
            qZ[1 - (PAR)][2] = qzeros[g1 * (OUTF / 8) + (col0 >> 3)];            \
            qZ[1 - (PAR)][3] = qzeros[g1 * (OUTF / 8) + (col1 >> 3)];            \
        }                                                                        \
        f16x2 hs2[2][2], hz2[2][2];                                              \
        _Pragma("unroll")                                                        \
        for (int gh = 0; gh < 2; ++gh)                                           \
            _Pragma("unroll")                                                    \
            for (int nf = 0; nf < 2; ++nf) {                                     \
                const float s = sS[PAR][gh * 2 + nf];                            \
                const int   z = (int)((qZ[PAR][gh * 2 + nf] >> zsh) & 15u) + 1025; \
                const _Float16 hs = (_Float16)s;                                 \
                const _Float16 hz = (_Float16)(-(float)z);                       \
                hs2[gh][nf] = f16x2{hs, hs};                                     \
                hz2[gh][nf] = f16x2{hz, hz};                                     \
            }                                                                    \
        const _Float16* buf = ldsW + (PAR) * 16384;                              \
        _Pragma("unroll")                                                        \
        for (int s = 0; s < 8; ++s) {                                            \
            const int gh = s >> 2;                                               \
            f16x8 af[4];                                                         \
            _Pragma("unroll")                                                    \
            for (int mi = 0; mi < 4; ++mi) {                                     \
                const int m  = mi * 16 + l16;                                    \
                const int sc = (s * 4 + quad) ^ fsw;                             \
                af[mi] = *(const f16x8*)(buf + m * 256 + sc * 8);                \
            }                                                                    \
            _Pragma("unroll")                                                    \
            for (int nf = 0; nf < 2; ++nf) {                                     \
                const uint32_t q = Breg[PAR][2 * s + nf];                        \
                H8 b;                                                            \
                _Pragma("unroll")                                                \
                for (int j = 0; j < 4; ++j) {                                    \
                    U32H2 u;                                                     \
                    u.u = ((q >> (4 * j)) & 0x000F000Fu) | 0x64006400u;          \
                    b.h2[j] = (u.h + hz2[gh][nf]) * hs2[gh][nf];                 \
                }                                                                \
                _Pragma("unroll")                                                \
                for (int mi = 0; mi < 4; ++mi)                                   \
                    acc[mi][nf] = __builtin_amdgcn_mfma_f32_16x16x32_f16(        \
                        af[mi], b.h8, acc[mi][nf], 0, 0, 0);                     \
            }                                                                    \
        }                                                                        \
        __syncthreads();                                                         \
    }

#pragma unroll 1
    for (int pp = 0; pp < NPHASE / 2; ++pp) {
        PHASE_BODY(0, 2 * pp, true)
        PHASE_BODY(1, 2 * pp + 1, (pp < NPHASE / 2 - 1))
    }
#undef PHASE_BODY

    // ================= epilogue =================
#pragma unroll
    for (int nf = 0; nf < 2; ++nf) {
        const int col = (nf == 0) ? col0 : col1;
        const float bv = bias[col];
#pragma unroll
        for (int mi = 0; mi < 4; ++mi) {
            const int r0 = by * 64 + mi * 16 + quad * 4;
#pragma unroll
            for (int rg = 0; rg < 4; ++rg)
                out[(size_t)(r0 + rg) * OUTF + col] = acc[mi][nf][rg] + bv;
        }
    }
}

// ---------------- fallback (proven R2 kernel) if ws too small ----------------
__global__ __launch_bounds__(NTH, 2)
void qlin_fb(const float* __restrict__ x,
             const uint32_t* __restrict__ qweight,
             const uint32_t* __restrict__ qzeros,
             const float* __restrict__ scales,
             const float* __restrict__ bias,
             float* __restrict__ out)
{
    __shared__ alignas(16) _Float16 Asb[64][40];
    __shared__ alignas(16) _Float16 Bsb[128][40];
    const int tid = threadIdx.x;
    const int bx = blockIdx.x, by = blockIdx.y;
    const int am = tid >> 2, ar = tid & 3;
    const float* xrow = x + (size_t)(by * 64 + am) * INF + ar * 8;
    const int bc = tid & 127, br = tid >> 7;
    const int bn = bx * 128 + bc;
    const int bswz = (bc >> 3) & 3;
    const int lane = tid & 63, quad = lane >> 4, l16 = lane & 15;
    const int wv = tid >> 6, wm = wv >> 1, wn = wv & 1;
    f32x4 acc[2][4];
#pragma unroll
    for (int i = 0; i < 2; ++i)
#pragma unroll
        for (int j = 0; j < 4; ++j) acc[i][j] = f32x4{0.f, 0.f, 0.f, 0.f};
    f32x4 pa0 = *(const f32x4*)(xrow + 0);
    f32x4 pa1 = *(const f32x4*)(xrow + 4);
    uint32_t pq0 = qweight[(size_t)br * OUTF + bn];
    uint32_t pq1 = qweight[(size_t)(br + 2) * OUTF + bn];
    for (int g = 0; g < NGROUPS; ++g) {
        const float s = scales[g * OUTF + bn];
        const uint32_t qzv = qzeros[g * (OUTF / 8) + (bn >> 3)];
        const int z = (int)((qzv >> (4 * (bn & 7))) & 15u) + 1;
        const _Float16 hs = (_Float16)s;
        const _Float16 hz = (_Float16)(-(float)(1024 + z));
        const f16x2 hs2 = {hs, hs}, hz2 = {hz, hz};
#pragma unroll
        for (int t4 = 0; t4 < 4; ++t4) {
            const int it = (g << 2) + t4;
            { H8 ah; PK p0, p1, p2, p3;
              p0.p = __builtin_amdgcn_cvt_pkrtz(pa0[0], pa1[0]);
              p1.p = __builtin_amdgcn_cvt_pkrtz(pa0[1], pa1[1]);
              p2.p = __builtin_amdgcn_cvt_pkrtz(pa0[2], pa1[2]);
              p3.p = __builtin_amdgcn_cvt_pkrtz(pa0[3], pa1[3]);
              ah.h2[0] = p0.h; ah.h2[1] = p1.h; ah.h2[2] = p2.h; ah.h2[3] = p3.h;
              *(f16x8*)&Asb[am][ar * 8] = ah.h8; }
            { const uint32_t qq[2] = {pq0, pq1};
#pragma unroll
              for (int rr = 0; rr < 2; ++rr) {
                  const int r = br + rr * 2; H8 bh;
#pragma unroll
                  for (int jp = 0; jp < 4; ++jp) {
                      U32H2 u; u.u = ((qq[rr] >> (4 * jp)) & 0x000F000Fu) | 0x64006400u;
                      bh.h2[jp] = (u.h + hz2) * hs2;
                  }
                  *(f16x8*)&Bsb[bc][(r ^ bswz) * 8] = bh.h8;
              } }
            __syncthreads();
            const int itn = (it < 127) ? it + 1 : 127;
            pa0 = *(const f32x4*)(xrow + itn * 32);
            pa1 = *(const f32x4*)(xrow + itn * 32 + 4);
            pq0 = qweight[(size_t)(itn * 4 + br) * OUTF + bn];
            pq1 = qweight[(size_t)(itn * 4 + br + 2) * OUTF + bn];
            f16x8 af[2], bf[4];
#pragma unroll
            for (int mi = 0; mi < 2; ++mi)
                af[mi] = *(const f16x8*)&Asb[wm * 32 + mi * 16 + l16][quad * 8];
#pragma unroll
            for (int ni = 0; ni < 4; ++ni) {
                const int c = wn * 64 + ni * 16 + l16;
                bf[ni] = *(const f16x8*)&Bsb[c][(quad ^ ((c >> 3) & 3)) * 8];
            }
#pragma unroll
            for (int mi = 0; mi < 2; ++mi)
#pragma unroll
                for (int ni = 0; ni < 4; ++ni)
                    acc[mi][ni] = __builtin_amdgcn_mfma_f32_16x16x32_f16(
                        af[mi], bf[ni], acc[mi][ni], 0, 0, 0);
            __syncthreads();
        }
    }
#pragma unroll
    for (int ni = 0; ni < 4; ++ni) {
        const int col = bx * 128 + wn * 64 + ni * 16 + l16;
        const float bv = bias[col];
#pragma unroll
        for (int mi = 0; mi < 2; ++mi) {
            const int row0 = by * 64 + wm * 32 + mi * 16 + quad * 4;
#pragma unroll
            for (int rg = 0; rg < 4; ++rg)
                out[(size_t)(row0 + rg) * OUTF + col] = acc[mi][ni][rg] + bv;
        }
    }
}

extern "C" void kernel_launch(void* const* d_in, const int* in_sizes, int n_in,
                              void* d_out, int out_size, void* d_ws, size_t ws_size,
                              hipStream_t stream) {
    const float*    xx = (const float*)d_in[0];
    const uint32_t* qw = (const uint32_t*)d_in[1];
    const uint32_t* qz = (const uint32_t*)d_in[2];
    const float*    sc = (const float*)d_in[3];
    const float*    bs = (const float*)d_in[4];
    float* out = (float*)d_out;

    const size_t x16_bytes = (size_t)TOKENS * INF * sizeof(_Float16);  // 2 MB
    if (ws_size >= x16_bytes) {
        _Float16* x16 = (_Float16*)d_ws;
        cvt_x<<<(TOKENS * INF / 8) / NTH, NTH, 0, stream>>>(xx, x16);
        qlin_main<<<(OUTF / 128) * (TOKENS / 64), NTH, 0, stream>>>(x16, qw, qz, sc, bs, out);
    } else {
        dim3 grid(OUTF / 128, TOKENS / 64);
        qlin_fb<<<grid, NTH, 0, stream>>>(xx, qw, qz, sc, bs, out);
    }
}